// Round 4
// baseline (662.137 us; speedup 1.0000x reference)
//
#include <hip/hip_runtime.h>
#include <math.h>

// ---------------- problem constants ----------------
constexpr int kN = 24000;     // nodes
constexpr int kE = 384000;    // edges
constexpr float kAlpha = 0.05f;

typedef unsigned int   u32;
typedef unsigned short u16;
typedef __attribute__((ext_vector_type(8))) short short8;
typedef __attribute__((ext_vector_type(4))) float float4v;

// ---- bf16 helpers (internal storage; RNE) ----
__device__ __forceinline__ float bf2f(u16 x) { return __uint_as_float(((u32)x) << 16); }
__device__ __forceinline__ u16 f2bf(float f) {
  u32 u = __float_as_uint(f);
  return (u16)((u + 0x7fffu + ((u >> 16) & 1u)) >> 16);
}
__device__ __forceinline__ void bfrow32(const u16* __restrict__ p, float* f) {
  const uint4* q = (const uint4*)p;
  #pragma unroll
  for (int i = 0; i < 4; ++i) {
    uint4 w = q[i];
    f[i*8+0] = bf2f((u16)(w.x & 0xffff)); f[i*8+1] = bf2f((u16)(w.x >> 16));
    f[i*8+2] = bf2f((u16)(w.y & 0xffff)); f[i*8+3] = bf2f((u16)(w.y >> 16));
    f[i*8+4] = bf2f((u16)(w.z & 0xffff)); f[i*8+5] = bf2f((u16)(w.z >> 16));
    f[i*8+6] = bf2f((u16)(w.w & 0xffff)); f[i*8+7] = bf2f((u16)(w.w >> 16));
  }
}

// ============================================================
// CSR build
// ============================================================
__global__ void __launch_bounds__(256) zero_ints_kernel(int* __restrict__ p, int n) {
  int i = blockIdx.x * 256 + threadIdx.x;
  if (i < n) p[i] = 0;
}

__global__ void __launch_bounds__(256) count_kernel(const int* __restrict__ dst,
                                                    int* __restrict__ counts) {
  int e = blockIdx.x * 256 + threadIdx.x;
  if (e < kE) atomicAdd(&counts[dst[e]], 1);
}

__global__ void __launch_bounds__(1024) scan_kernel(const int* __restrict__ counts,
                                                    int* __restrict__ row_start) {
  __shared__ int wsum[16];
  __shared__ int carry_s;
  int tid = threadIdx.x, lane = tid & 63, wid = tid >> 6;
  if (tid == 0) { carry_s = 0; row_start[0] = 0; }
  __syncthreads();
  for (int base = 0; base < kN; base += 1024) {
    int x = (base + tid < kN) ? counts[base + tid] : 0;
    #pragma unroll
    for (int off = 1; off < 64; off <<= 1) {
      int y = __shfl_up(x, off);
      if (lane >= off) x += y;
    }
    if (lane == 63) wsum[wid] = x;
    __syncthreads();
    if (tid < 16) {
      int wv = wsum[tid];
      #pragma unroll
      for (int off = 1; off < 16; off <<= 1) {
        int y = __shfl_up(wv, off);
        if (tid >= off) wv += y;
      }
      wsum[tid] = wv;
    }
    __syncthreads();
    int incl = x + carry_s + (wid > 0 ? wsum[wid - 1] : 0);
    if (base + tid < kN) row_start[base + tid + 1] = incl;
    __syncthreads();
    if (tid == 1023) carry_s = incl;
    __syncthreads();
  }
}

__global__ void __launch_bounds__(256) scatter_kernel(const int* __restrict__ dst,
                                                      const int* __restrict__ row_start,
                                                      int* __restrict__ cursor,
                                                      int* __restrict__ edge_ids) {
  int e = blockIdx.x * 256 + threadIdx.x;
  if (e < kE) {
    int n = dst[e];
    int pos = row_start[n] + atomicAdd(&cursor[n], 1);
    edge_ids[pos] = e;
  }
}

// ============================================================
// Merged precompute + weight-pack.
// Blocks 0..743: pack WT0/WT1/WT2 (bf16 B-transposed, + el/er/res cols).
// Block 744: ntf, eterm (2-stage factorization), DA delta.
// ============================================================
__global__ void __launch_bounds__(256) prepack_kernel(
    const float* __restrict__ W0, const float* __restrict__ al0, const float* __restrict__ ar0,
    const float* __restrict__ W1, const float* __restrict__ al1, const float* __restrict__ ar1,
    const float* __restrict__ rW1,
    const float* __restrict__ W2, const float* __restrict__ al2, const float* __restrict__ ar2,
    const float* __restrict__ rW2,
    u16* __restrict__ WT0, u16* __restrict__ WT1, u16* __restrict__ WT2,
    const float* __restrict__ ntype_emb, const float* __restrict__ W_ntype,
    const float* __restrict__ emb0, const float* __restrict__ We0, const float* __restrict__ ae0,
    const float* __restrict__ emb1, const float* __restrict__ We1, const float* __restrict__ ae1,
    const float* __restrict__ emb2, const float* __restrict__ We2, const float* __restrict__ ae2,
    const float* __restrict__ ln1_b, const float* __restrict__ Wv, const float* __restrict__ bv,
    const float* __restrict__ Wo, const float* __restrict__ bo,
    const float* __restrict__ ln2_b, const float* __restrict__ DW1, const float* __restrict__ Db1,
    const float* __restrict__ DW2, const float* __restrict__ Db2,
    float* __restrict__ ntf, float* __restrict__ eterm, float* __restrict__ dadelta) {
  __shared__ float wae[17][64];
  __shared__ float red[128];
  int tid = threadIdx.x;
  if (blockIdx.x < 744) {
    const int SZ0 = 320 * 32, SZ1 = 576 * 256;
    int gid = blockIdx.x * 256 + tid;
    float v = 0.f;
    if (gid < SZ0) {
      int n = gid / 32, k = gid % 32;
      if (n < 256) v = W0[k * 256 + n];
      else if (n < 264) { int h = n - 256; for (int d = 0; d < 32; ++d) v += W0[k * 256 + h * 32 + d] * al0[h * 32 + d]; }
      else if (n < 272) { int h = n - 264; for (int d = 0; d < 32; ++d) v += W0[k * 256 + h * 32 + d] * ar0[h * 32 + d]; }
      WT0[n * 32 + k] = f2bf(v);
    } else if (gid < SZ0 + SZ1) {
      int i = gid - SZ0;
      int n = i / 256, k = i % 256;
      if (n < 256) v = W1[k * 256 + n];
      else if (n < 264) { int h = n - 256; for (int d = 0; d < 32; ++d) v += W1[k * 256 + h * 32 + d] * al1[h * 32 + d]; }
      else if (n < 272) { int h = n - 264; for (int d = 0; d < 32; ++d) v += W1[k * 256 + h * 32 + d] * ar1[h * 32 + d]; }
      else if (n < 528) v = rW1[k * 256 + (n - 272)];
      WT1[n * 256 + k] = f2bf(v);
    } else {
      int i = gid - SZ0 - SZ1;
      int n = i / 256, k = i % 256;
      if (n < 32) v = W2[k * 32 + n];
      else if (n == 32) { for (int d = 0; d < 32; ++d) v += W2[k * 32 + d] * al2[d]; }
      else if (n == 33) { for (int d = 0; d < 32; ++d) v += W2[k * 32 + d] * ar2[d]; }
      else if (n < 66) v = rW2[k * 32 + (n - 34)];
      WT2[n * 256 + k] = f2bf(v);
    }
  } else {
    // precompute block
    for (int idx = tid; idx < 17 * 64; idx += 256) {
      int hg = idx >> 6, k = idx & 63;
      const float* We; const float* ae; int Hh, h;
      if (hg < 8)       { We = We0; ae = ae0; Hh = 8; h = hg; }
      else if (hg < 16) { We = We1; ae = ae1; Hh = 8; h = hg - 8; }
      else              { We = We2; ae = ae2; Hh = 1; h = 0; }
      float s = 0.f;
      for (int d = 0; d < 64; ++d) s += We[(size_t)k * Hh * 64 + h * 64 + d] * ae[h * 64 + d];
      wae[hg][k] = s;
    }
    __syncthreads();
    for (int id = tid; id < 85; id += 256) {
      const float* emb; int Hh, t, h, hg, base;
      if (id < 40)      { emb = emb0; Hh = 8; t = id / 8;  h = id % 8; hg = h;      base = 0;  }
      else if (id < 80) { int i = id - 40; emb = emb1; Hh = 8; t = i / 8; h = i % 8; hg = 8 + h; base = 40; }
      else              { int i = id - 80; emb = emb2; Hh = 1; t = i;    h = 0;     hg = 16;    base = 80; }
      float s = 0.f;
      for (int k = 0; k < 64; ++k) s += emb[t * 64 + k] * wae[hg][k];
      eterm[base + t * Hh + h] = s;
    }
    for (int idx = tid; idx < 96; idx += 256) {
      int t = idx / 32, o = idx % 32;
      float s = 0.f;
      for (int k = 0; k < 32; ++k) s += ntype_emb[t * 32 + k] * W_ntype[k * 32 + o];
      ntf[idx] = s;
    }
    for (int i2 = tid; i2 < 128; i2 += 256) {
      int l = i2 >> 6, j = i2 & 63;
      float u = ln2_b[l] * DW1[l * 64 + j] + Db1[l * 64 + j];
      float g = 0.5f * u * (1.0f + erff(u * 0.7071067811865476f));
      red[i2] = g * DW2[l * 64 + j];
    }
    __syncthreads();
    if (tid == 0) {
      float delta = 0.f;
      for (int l = 0; l < 2; ++l) {
        float vs = ln1_b[l] * Wv[l] + bv[l];
        delta += vs * Wo[l] + bo[l] + Db2[l];
      }
      for (int i = 0; i < 128; ++i) delta += red[i];
      *dadelta = delta;
    }
  }
}

// ============================================================
// Input projection -> Hb bf16
// ============================================================
__global__ void __launch_bounds__(256) inproj_kernel(
    const float* __restrict__ feats, const float* __restrict__ fc_W,
    const float* __restrict__ fc_b, const float* __restrict__ ntf,
    const int* __restrict__ node_type, u16* __restrict__ hb) {
  int t = blockIdx.x * 256 + threadIdx.x;
  if (t >= kN * 32) return;
  int n = t >> 5, o = t & 31;
  int ty = n / 8000;
  const float* fr = &feats[(size_t)n * 128];
  const float* w  = &fc_W[(size_t)ty * 4096 + o];
  float s = fc_b[ty * 32 + o];
  #pragma unroll
  for (int k = 0; k < 128; k += 4) {
    float4 f = *(const float4*)&fr[k];
    s += f.x * w[(k + 0) * 32] + f.y * w[(k + 1) * 32]
       + f.z * w[(k + 2) * 32] + f.w * w[(k + 3) * 32];
  }
  s = (s < 0.f) ? 0.01f * s : s;
  hb[t] = f2bf(s * ntf[node_type[n] * 32 + o]);
}

// ============================================================
// bf16 MFMA GEMM, whole-K LDS staging, ONE barrier per block.
//   cols [0,N1) -> featb bf16; [N1,N1+HH) -> el; [..+HH) -> er;
//   [..,..+N2) -> res+bias -> resb bf16 / resf f32.
// 64x64 tile, 4 waves (2x2), each 32x32 via 2x2 16x16x32 frags.
// XOR-swizzled LDS (T2) for conflict-free ds_read_b128.
// ============================================================
template <int K>
__global__ void __launch_bounds__(256) mfma_gemm_kernel(
    const u16* __restrict__ A, const u16* __restrict__ WT,
    const float* __restrict__ bias,
    u16* __restrict__ featb, float* __restrict__ el, float* __restrict__ er,
    u16* __restrict__ resb, float* __restrict__ resf,
    int N1, int HH, int N2) {
  constexpr int RB = K * 2;            // row bytes
  constexpr int CPR = K / 8;           // 16B chunks per row
  __shared__ __align__(16) u16 As[64 * K];
  __shared__ __align__(16) u16 Bs[64 * K];
  const int tid = threadIdx.x;
  const int l = tid & 63;
  const int w = tid >> 6;
  const int wm = w >> 1, wn = w & 1;
  const int m0 = blockIdx.y * 64;
  const int n0 = blockIdx.x * 64;
  const int kslot = l >> 4;
  const int l15 = l & 15;

  // stage A and B tiles fully (coalesced global, swizzled LDS)
  #pragma unroll
  for (int c = tid; c < 64 * CPR; c += 256) {
    int row = c / CPR, ch = c - row * CPR;
    int off = (row * RB + ch * 16) ^ ((row & 7) << 4);
    uint4 va = *(const uint4*)(A + (size_t)(m0 + row) * K + ch * 8);
    *(uint4*)((char*)As + off) = va;
    uint4 vb = *(const uint4*)(WT + (size_t)(n0 + row) * K + ch * 8);
    *(uint4*)((char*)Bs + off) = vb;
  }
  __syncthreads();

  float4v acc[2][2];
  #pragma unroll
  for (int f = 0; f < 2; ++f)
    #pragma unroll
    for (int g = 0; g < 2; ++g) { acc[f][g][0]=0.f; acc[f][g][1]=0.f; acc[f][g][2]=0.f; acc[f][g][3]=0.f; }

  #pragma unroll
  for (int kc = 0; kc < K; kc += 32) {
    short8 af[2], bf[2];
    #pragma unroll
    for (int f = 0; f < 2; ++f) {
      int row = wm * 32 + f * 16 + l15;
      int off = (row * RB + kc * 2 + kslot * 16) ^ ((row & 7) << 4);
      af[f] = *(const short8*)((const char*)As + off);
    }
    #pragma unroll
    for (int g = 0; g < 2; ++g) {
      int n = wn * 32 + g * 16 + l15;
      int off = (n * RB + kc * 2 + kslot * 16) ^ ((n & 7) << 4);
      bf[g] = *(const short8*)((const char*)Bs + off);
    }
    #pragma unroll
    for (int f = 0; f < 2; ++f)
      #pragma unroll
      for (int g = 0; g < 2; ++g)
        acc[f][g] = __builtin_amdgcn_mfma_f32_16x16x32_bf16(af[f], bf[g], acc[f][g], 0, 0, 0);
  }

  const int rbase = kslot * 4;
  #pragma unroll
  for (int f = 0; f < 2; ++f) {
    #pragma unroll
    for (int g = 0; g < 2; ++g) {
      int gc = n0 + wn * 32 + g * 16 + l15;
      #pragma unroll
      for (int reg = 0; reg < 4; ++reg) {
        int gr = m0 + wm * 32 + f * 16 + rbase + reg;
        float v = acc[f][g][reg];
        if (gc < N1) {
          featb[(size_t)gr * N1 + gc] = f2bf(v);
        } else if (gc < N1 + HH) {
          el[(size_t)gr * HH + (gc - N1)] = v;
        } else if (gc < N1 + 2 * HH) {
          er[(size_t)gr * HH + (gc - N1 - HH)] = v;
        } else if (gc < N1 + 2 * HH + N2) {
          int c2 = gc - N1 - 2 * HH;
          float vv = v + bias[c2];
          if (resb) resb[(size_t)gr * N2 + c2] = f2bf(vv);
          else      resf[(size_t)gr * N2 + c2] = vv;
        }
      }
    }
  }
}

// ============================================================
// Edge-softmax aggregation (HH=8): TWO waves per node, 4 heads each.
// lane = hh*16+q: head hbase+hh, dim pair q (dims 2q,2q+1).
// Pass1: 16 lanes/head stride edges; shfl_xor(1,2,4,8) merge.
// Pass2: depth-2 pipelined gather; 256B coalesced featb read/edge/wave.
// ============================================================
template <bool WRITE_A0, bool READ_A0, bool BIAS_INIT, bool ACT>
__global__ void __launch_bounds__(256) agg8w_kernel(
    const int* __restrict__ row_start, const int* __restrict__ edge_ids,
    const int* __restrict__ src, const int* __restrict__ ef,
    const float* __restrict__ el, const float* __restrict__ er,
    const float* __restrict__ eterm,        // [NE][8]
    const u16* __restrict__ featb,          // [N][256] bf16
    const float* __restrict__ bias,         // [256] (BIAS_INIT)
    _Float16* __restrict__ a0h,             // [E][8]
    const u16* __restrict__ accb,           // [N][256] bf16 (else)
    u16* __restrict__ outb) {               // [N][256] bf16
  int gw = (blockIdx.x * 256 + threadIdx.x) >> 6;
  if (gw >= kN * 2) return;
  int n = gw >> 1, half = gw & 1;
  int l = threadIdx.x & 63;
  int h = half * 4 + (l >> 4);
  int q = l & 15;
  int s0 = row_start[n], s1 = row_start[n + 1];
  float ern = er[n * 8 + h];
  // eterm values in registers (NE=5)
  float et0 = eterm[0 * 8 + h], et1 = eterm[1 * 8 + h], et2 = eterm[2 * 8 + h];
  float et3 = eterm[3 * 8 + h], et4 = eterm[4 * 8 + h];
  // pass 1: per-lane online (max,sum) over every 16th edge
  float m = -1e30f, ssum = 0.f;
  for (int i = s0 + q; i < s1; i += 16) {
    int e = edge_ids[i];
    int efc = ef[e];
    float etv = (efc == 0) ? et0 : (efc == 1) ? et1 : (efc == 2) ? et2 : (efc == 3) ? et3 : et4;
    float lg = el[src[e] * 8 + h] + ern + etv;
    lg = (lg < 0.f) ? 0.2f * lg : lg;
    if (lg > m) { ssum = ssum * expf(m - lg) + 1.f; m = lg; }
    else        { ssum += expf(lg - m); }
  }
  #pragma unroll
  for (int mk = 1; mk <= 8; mk <<= 1) {
    float om = __shfl_xor(m, mk);
    float os = __shfl_xor(ssum, mk);
    float nm = fmaxf(m, om);
    ssum = ssum * expf(m - nm) + os * expf(om - nm);
    m = nm;
  }
  float inv = 1.f / ssum;
  // acc init (2 dims per lane)
  float ax, ay;
  const size_t rowoff = (size_t)n * 256 + h * 32 + q * 2;
  if (BIAS_INIT) {
    ax = bias[h * 32 + q * 2]; ay = bias[h * 32 + q * 2 + 1];
  } else {
    u32 rv = *(const u32*)(accb + rowoff);
    ax = bf2f((u16)(rv & 0xffff)); ay = bf2f((u16)(rv >> 16));
  }
  // pass 2: depth-2 pipeline on (e, se, ef)
  int e0 = 0, se0 = 0, ef0 = 0, e1 = 0, se1 = 0, ef1 = 0;
  if (s0 < s1)     { e0 = edge_ids[s0];     se0 = src[e0]; ef0 = ef[e0]; }
  if (s0 + 1 < s1) { e1 = edge_ids[s0 + 1]; se1 = src[e1]; ef1 = ef[e1]; }
  for (int i = s0; i < s1; ++i) {
    int e = e0, se = se0, efc = ef0;
    e0 = e1; se0 = se1; ef0 = ef1;
    if (i + 2 < s1) { e1 = edge_ids[i + 2]; se1 = src[e1]; ef1 = ef[e1]; }
    float elv = el[se * 8 + h];
    u32 fv = *(const u32*)(featb + (size_t)se * 256 + h * 32 + q * 2);
    float etv = (efc == 0) ? et0 : (efc == 1) ? et1 : (efc == 2) ? et2 : (efc == 3) ? et3 : et4;
    float lg = elv + ern + etv;
    lg = (lg < 0.f) ? 0.2f * lg : lg;
    float a = expf(lg - m) * inv;
    if (WRITE_A0) { if (q == 0) a0h[(size_t)e * 8 + h] = (_Float16)a; }
    if (READ_A0)  a = a * (1.f - kAlpha) + (float)a0h[(size_t)e * 8 + h] * kAlpha;
    ax = fmaf(a, bf2f((u16)(fv & 0xffff)), ax);
    ay = fmaf(a, bf2f((u16)(fv >> 16)), ay);
  }
  if (ACT) {
    ax = (ax > 0.f) ? ax : expm1f(ax);
    ay = (ay > 0.f) ? ay : expm1f(ay);
  }
  u32 pw = (u32)f2bf(ax) | ((u32)f2bf(ay) << 16);
  *(u32*)(outb + rowoff) = pw;
}

// ============================================================
// Fused L2 aggregation (HH=1, thread-per-node) + final head.
// ============================================================
__global__ void __launch_bounds__(256) agg1t_final_kernel(
    const int* __restrict__ row_start, const int* __restrict__ edge_ids,
    const int* __restrict__ src, const int* __restrict__ ef,
    const float* __restrict__ el, const float* __restrict__ er,
    const float* __restrict__ eterm,        // [NE]
    const u16* __restrict__ featb,          // [N][32] bf16
    const float* __restrict__ S2,           // [N][32] f32 (res+bias)
    const float* __restrict__ ntf, const int* __restrict__ node_type,
    const float* __restrict__ dadelta,
    const float* __restrict__ finalW, const float* __restrict__ logitsW,
    float* __restrict__ out) {
  int n = blockIdx.x * 256 + threadIdx.x;
  if (n >= kN) return;
  int s0 = row_start[n], s1 = row_start[n + 1];
  float ern = er[n];
  float et0 = eterm[0], et1 = eterm[1], et2 = eterm[2], et3 = eterm[3], et4 = eterm[4];
  float acc[32];
  #pragma unroll
  for (int d2 = 0; d2 < 8; ++d2) {
    float4 v = *(const float4*)&S2[(size_t)n * 32 + d2 * 4];
    acc[d2*4] = v.x; acc[d2*4+1] = v.y; acc[d2*4+2] = v.z; acc[d2*4+3] = v.w;
  }
  if (s0 < s1) {
    float m = -1e30f, ssum = 0.f;
    for (int i = s0; i < s1; ++i) {
      int e = edge_ids[i];
      int efc = ef[e];
      float etv = (efc == 0) ? et0 : (efc == 1) ? et1 : (efc == 2) ? et2 : (efc == 3) ? et3 : et4;
      float lg = el[src[e]] + ern + etv;
      lg = (lg < 0.f) ? 0.2f * lg : lg;
      if (lg > m) { ssum = ssum * expf(m - lg) + 1.f; m = lg; }
      else        { ssum += expf(lg - m); }
    }
    float inv = 1.f / ssum;
    int e0 = 0, se0 = 0, ef0 = 0;
    e0 = edge_ids[s0]; se0 = src[e0]; ef0 = ef[e0];
    for (int i = s0; i < s1; ++i) {
      int e = e0, se = se0, efc = ef0;
      if (i + 1 < s1) { e0 = edge_ids[i + 1]; se0 = src[e0]; ef0 = ef[e0]; }
      float etv = (efc == 0) ? et0 : (efc == 1) ? et1 : (efc == 2) ? et2 : (efc == 3) ? et3 : et4;
      float lg = el[se] + ern + etv;
      lg = (lg < 0.f) ? 0.2f * lg : lg;
      float a = expf(lg - m) * inv;
      float f[32];
      bfrow32(&featb[(size_t)se * 32], f);
      #pragma unroll
      for (int d = 0; d < 32; ++d) acc[d] = fmaf(a, f[d], acc[d]);
    }
  }
  // ---- final head ----
  float delta = dadelta[0];
  const float* nt = &ntf[node_type[n] * 32];
  float a_[32], b_[32];
  float na = 0.f, nb = 0.f;
  #pragma unroll
  for (int d = 0; d < 32; ++d) {
    float x = acc[d];
    a_[d] = x; na += x * x;
    float y = x * nt[d] + delta;
    b_[d] = y; nb += y * y;
  }
  float inva = 1.f / fmaxf(sqrtf(na), 1e-12f);
  float invb = 1.f / fmaxf(sqrtf(nb), 1e-12f);
  #pragma unroll
  for (int d = 0; d < 32; ++d) { a_[d] *= inva; b_[d] *= invb; }
  float lg[16];
  #pragma unroll
  for (int c = 0; c < 16; ++c) lg[c] = 0.f;
  for (int o = 0; o < 32; ++o) {
    float s = 0.f;
    #pragma unroll
    for (int d = 0; d < 32; ++d)
      s += a_[d] * finalW[d * 32 + o] + b_[d] * finalW[(32 + d) * 32 + o];
    s = fmaxf(s, 0.f);
    #pragma unroll
    for (int c = 0; c < 16; ++c) lg[c] += s * logitsW[o * 16 + c];
  }
  float nl = 0.f;
  #pragma unroll
  for (int c = 0; c < 16; ++c) nl += lg[c] * lg[c];
  float invl = 1.f / fmaxf(sqrtf(nl), 1e-12f);
  #pragma unroll
  for (int c = 0; c < 16; ++c) out[(size_t)n * 16 + c] = lg[c] * invl;
}

// ============================================================
extern "C" void kernel_launch(void* const* d_in, const int* in_sizes, int n_in,
                              void* d_out, int out_size, void* d_ws, size_t ws_size,
                              hipStream_t stream) {
  const float* feats     = (const float*)d_in[0];
  const int*   e_feat    = (const int*)d_in[1];
  const int*   node_type = (const int*)d_in[2];
  const int*   src       = (const int*)d_in[3];
  const int*   dst       = (const int*)d_in[4];
  const float* fc_W      = (const float*)d_in[5];
  const float* fc_b      = (const float*)d_in[6];
  const float* ntype_emb = (const float*)d_in[7];
  const float* W_ntype   = (const float*)d_in[8];
  const float* ta_edge_emb[3] = {(const float*)d_in[9],  (const float*)d_in[16], (const float*)d_in[24]};
  const float* ta_W[3]        = {(const float*)d_in[10], (const float*)d_in[17], (const float*)d_in[25]};
  const float* ta_We[3]       = {(const float*)d_in[11], (const float*)d_in[18], (const float*)d_in[26]};
  const float* ta_al[3]       = {(const float*)d_in[12], (const float*)d_in[19], (const float*)d_in[27]};
  const float* ta_ar[3]       = {(const float*)d_in[13], (const float*)d_in[20], (const float*)d_in[28]};
  const float* ta_ae[3]       = {(const float*)d_in[14], (const float*)d_in[21], (const float*)d_in[29]};
  const float* ta_bias[3]     = {(const float*)d_in[15], (const float*)d_in[22], (const float*)d_in[30]};
  const float* ta1_res_W = (const float*)d_in[23];
  const float* ta2_res_W = (const float*)d_in[31];
  const float* da_ln1_b  = (const float*)d_in[33];
  const float* da_Wv     = (const float*)d_in[38];
  const float* da_bv     = (const float*)d_in[39];
  const float* da_Wo     = (const float*)d_in[40];
  const float* da_bo     = (const float*)d_in[41];
  const float* da_ln2_b  = (const float*)d_in[43];
  const float* da_W1     = (const float*)d_in[44];
  const float* da_b1     = (const float*)d_in[45];
  const float* da_W2     = (const float*)d_in[46];
  const float* da_b2     = (const float*)d_in[47];
  const float* final_W   = (const float*)d_in[48];
  const float* logits_W  = (const float*)d_in[49];
  float* out = (float*)d_out;

  // ---- workspace layout (~51.3 MB, proven safe) ----
  char* base = (char*)d_ws;
  int* iws       = (int*)base;
  int* counts    = iws;
  int* cursor    = iws + kN;
  int* row_start = iws + 2 * kN;
  int* edge_ids  = iws + 2 * kN + kN + 1;
  char* p = base + (size_t)456004 * 4;
  float* ntf = (float*)p;                     p += 512;
  float* etm = (float*)p;                     p += 512;
  float* dad = (float*)p;                     p += 64;
  float* el  = (float*)p;                     p += (size_t)kN * 8 * 4;
  float* er  = (float*)p;                     p += (size_t)kN * 8 * 4;
  float* S2  = (float*)p;                     p += (size_t)kN * 32 * 4;
  u16*   Hb  = (u16*)p;                       p += (size_t)kN * 32 * 2;
  _Float16* a0h = (_Float16*)p;               p += (size_t)kE * 8 * 2;
  u16* featb = (u16*)p;                       p += (size_t)kN * 256 * 2;
  u16* Rb0   = (u16*)p;                       p += (size_t)kN * 256 * 2;
  u16* Rpr   = (u16*)p;                       p += (size_t)kN * 256 * 2;
  u16* WT0   = (u16*)p;                       p += (size_t)320 * 32 * 2;
  u16* WT1   = (u16*)p;                       p += (size_t)576 * 256 * 2;
  u16* WT2   = (u16*)p;                       p += (size_t)128 * 256 * 2;

  // --- CSR build ---
  zero_ints_kernel<<<(2 * kN + 255) / 256, 256, 0, stream>>>(counts, 2 * kN);
  count_kernel<<<kE / 256, 256, 0, stream>>>(dst, counts);
  scan_kernel<<<1, 1024, 0, stream>>>(counts, row_start);
  scatter_kernel<<<kE / 256, 256, 0, stream>>>(dst, row_start, cursor, edge_ids);

  // --- merged precompute + pack ---
  prepack_kernel<<<745, 256, 0, stream>>>(
      ta_W[0], ta_al[0], ta_ar[0],
      ta_W[1], ta_al[1], ta_ar[1], ta1_res_W,
      ta_W[2], ta_al[2], ta_ar[2], ta2_res_W,
      WT0, WT1, WT2,
      ntype_emb, W_ntype,
      ta_edge_emb[0], ta_We[0], ta_ae[0],
      ta_edge_emb[1], ta_We[1], ta_ae[1],
      ta_edge_emb[2], ta_We[2], ta_ae[2],
      da_ln1_b, da_Wv, da_bv, da_Wo, da_bo,
      da_ln2_b, da_W1, da_b1, da_W2, da_b2,
      ntf, etm, dad);

  // --- input projection -> Hb bf16 ---
  inproj_kernel<<<(kN * 32) / 256, 256, 0, stream>>>(feats, fc_W, fc_b, ntf, node_type, Hb);

  // --- TA layer 0: GEMM (feat+el+er) then 2-wave agg (bias init, elu, write a0) ---
  mfma_gemm_kernel<32><<<dim3(5, kN / 64), 256, 0, stream>>>(
      Hb, WT0, nullptr, featb, el, er, nullptr, nullptr, 256, 8, 0);
  agg8w_kernel<true, false, true, true><<<kN / 2, 256, 0, stream>>>(
      row_start, edge_ids, src, e_feat, el, er, etm, featb, ta_bias[0], a0h, nullptr, Rb0);

  // --- TA layer 1: fused GEMM (feat+el+er+res) then 2-wave agg (acc=res, blend a0, elu) ---
  mfma_gemm_kernel<256><<<dim3(9, kN / 64), 256, 0, stream>>>(
      Rb0, WT1, ta_bias[1], featb, el, er, Rpr, nullptr, 256, 8, 256);
  agg8w_kernel<false, true, false, true><<<kN / 2, 256, 0, stream>>>(
      row_start, edge_ids, src, e_feat, el, er, etm + 40, featb, nullptr, a0h, Rpr, Rpr);

  // --- TA layer 2: fused GEMM (feat+el+er+res f32) then fused agg+final ---
  mfma_gemm_kernel<256><<<dim3(2, kN / 64), 256, 0, stream>>>(
      Rpr, WT2, ta_bias[2], featb, el, er, nullptr, S2, 32, 1, 32);
  agg1t_final_kernel<<<(kN + 255) / 256, 256, 0, stream>>>(
      row_start, edge_ids, src, e_feat, el, er, etm + 80, featb, S2,
      ntf, node_type, dad, final_W, logits_W, out);
}

// Round 5
// 517.103 us; speedup vs baseline: 1.2805x; 1.2805x over previous
//
#include <hip/hip_runtime.h>
#include <math.h>

// ---------------- problem constants ----------------
constexpr int kN = 24000;     // nodes
constexpr int kE = 384000;    // edges
constexpr float kAlpha = 0.05f;

typedef unsigned int   u32;
typedef unsigned short u16;
typedef __attribute__((ext_vector_type(8))) short short8;
typedef __attribute__((ext_vector_type(4))) float float4v;

// ---- bf16 helpers (internal storage; RNE) ----
__device__ __forceinline__ float bf2f(u16 x) { return __uint_as_float(((u32)x) << 16); }
__device__ __forceinline__ u16 f2bf(float f) {
  u32 u = __float_as_uint(f);
  return (u16)((u + 0x7fffu + ((u >> 16) & 1u)) >> 16);
}
__device__ __forceinline__ void bfrow32(const u16* __restrict__ p, float* f) {
  const uint4* q = (const uint4*)p;
  #pragma unroll
  for (int i = 0; i < 4; ++i) {
    uint4 w = q[i];
    f[i*8+0] = bf2f((u16)(w.x & 0xffff)); f[i*8+1] = bf2f((u16)(w.x >> 16));
    f[i*8+2] = bf2f((u16)(w.y & 0xffff)); f[i*8+3] = bf2f((u16)(w.y >> 16));
    f[i*8+4] = bf2f((u16)(w.z & 0xffff)); f[i*8+5] = bf2f((u16)(w.z >> 16));
    f[i*8+6] = bf2f((u16)(w.w & 0xffff)); f[i*8+7] = bf2f((u16)(w.w >> 16));
  }
}

// ============================================================
// CSR build
// ============================================================
__global__ void __launch_bounds__(256) zero_ints_kernel(int* __restrict__ p, int n) {
  int i = blockIdx.x * 256 + threadIdx.x;
  if (i < n) p[i] = 0;
}

__global__ void __launch_bounds__(256) count_kernel(const int* __restrict__ dst,
                                                    int* __restrict__ counts) {
  int e = blockIdx.x * 256 + threadIdx.x;
  if (e < kE) atomicAdd(&counts[dst[e]], 1);
}

__global__ void __launch_bounds__(1024) scan_kernel(const int* __restrict__ counts,
                                                    int* __restrict__ row_start) {
  __shared__ int wsum[16];
  __shared__ int carry_s;
  int tid = threadIdx.x, lane = tid & 63, wid = tid >> 6;
  if (tid == 0) { carry_s = 0; row_start[0] = 0; }
  __syncthreads();
  for (int base = 0; base < kN; base += 1024) {
    int x = (base + tid < kN) ? counts[base + tid] : 0;
    #pragma unroll
    for (int off = 1; off < 64; off <<= 1) {
      int y = __shfl_up(x, off);
      if (lane >= off) x += y;
    }
    if (lane == 63) wsum[wid] = x;
    __syncthreads();
    if (tid < 16) {
      int wv = wsum[tid];
      #pragma unroll
      for (int off = 1; off < 16; off <<= 1) {
        int y = __shfl_up(wv, off);
        if (tid >= off) wv += y;
      }
      wsum[tid] = wv;
    }
    __syncthreads();
    int incl = x + carry_s + (wid > 0 ? wsum[wid - 1] : 0);
    if (base + tid < kN) row_start[base + tid + 1] = incl;
    __syncthreads();
    if (tid == 1023) carry_s = incl;
    __syncthreads();
  }
}

__global__ void __launch_bounds__(256) scatter_kernel(const int* __restrict__ dst,
                                                      const int* __restrict__ row_start,
                                                      int* __restrict__ cursor,
                                                      int* __restrict__ edge_ids) {
  int e = blockIdx.x * 256 + threadIdx.x;
  if (e < kE) {
    int n = dst[e];
    int pos = row_start[n] + atomicAdd(&cursor[n], 1);
    edge_ids[pos] = e;
  }
}

// ============================================================
// Merged precompute + weight-pack.
// Blocks 0..743: pack WT0/WT1/WT2 (bf16 B-transposed, + el/er/res cols).
// Block 744: ntf, eterm (2-stage factorization), DA delta.
// ============================================================
__global__ void __launch_bounds__(256) prepack_kernel(
    const float* __restrict__ W0, const float* __restrict__ al0, const float* __restrict__ ar0,
    const float* __restrict__ W1, const float* __restrict__ al1, const float* __restrict__ ar1,
    const float* __restrict__ rW1,
    const float* __restrict__ W2, const float* __restrict__ al2, const float* __restrict__ ar2,
    const float* __restrict__ rW2,
    u16* __restrict__ WT0, u16* __restrict__ WT1, u16* __restrict__ WT2,
    const float* __restrict__ ntype_emb, const float* __restrict__ W_ntype,
    const float* __restrict__ emb0, const float* __restrict__ We0, const float* __restrict__ ae0,
    const float* __restrict__ emb1, const float* __restrict__ We1, const float* __restrict__ ae1,
    const float* __restrict__ emb2, const float* __restrict__ We2, const float* __restrict__ ae2,
    const float* __restrict__ ln1_b, const float* __restrict__ Wv, const float* __restrict__ bv,
    const float* __restrict__ Wo, const float* __restrict__ bo,
    const float* __restrict__ ln2_b, const float* __restrict__ DW1, const float* __restrict__ Db1,
    const float* __restrict__ DW2, const float* __restrict__ Db2,
    float* __restrict__ ntf, float* __restrict__ eterm, float* __restrict__ dadelta) {
  __shared__ float wae[17][64];
  __shared__ float red[128];
  int tid = threadIdx.x;
  if (blockIdx.x < 744) {
    const int SZ0 = 320 * 32, SZ1 = 576 * 256;
    int gid = blockIdx.x * 256 + tid;
    float v = 0.f;
    if (gid < SZ0) {
      int n = gid / 32, k = gid % 32;
      if (n < 256) v = W0[k * 256 + n];
      else if (n < 264) { int h = n - 256; for (int d = 0; d < 32; ++d) v += W0[k * 256 + h * 32 + d] * al0[h * 32 + d]; }
      else if (n < 272) { int h = n - 264; for (int d = 0; d < 32; ++d) v += W0[k * 256 + h * 32 + d] * ar0[h * 32 + d]; }
      WT0[n * 32 + k] = f2bf(v);
    } else if (gid < SZ0 + SZ1) {
      int i = gid - SZ0;
      int n = i / 256, k = i % 256;
      if (n < 256) v = W1[k * 256 + n];
      else if (n < 264) { int h = n - 256; for (int d = 0; d < 32; ++d) v += W1[k * 256 + h * 32 + d] * al1[h * 32 + d]; }
      else if (n < 272) { int h = n - 264; for (int d = 0; d < 32; ++d) v += W1[k * 256 + h * 32 + d] * ar1[h * 32 + d]; }
      else if (n < 528) v = rW1[k * 256 + (n - 272)];
      WT1[n * 256 + k] = f2bf(v);
    } else {
      int i = gid - SZ0 - SZ1;
      int n = i / 256, k = i % 256;
      if (n < 32) v = W2[k * 32 + n];
      else if (n == 32) { for (int d = 0; d < 32; ++d) v += W2[k * 32 + d] * al2[d]; }
      else if (n == 33) { for (int d = 0; d < 32; ++d) v += W2[k * 32 + d] * ar2[d]; }
      else if (n < 66) v = rW2[k * 32 + (n - 34)];
      WT2[n * 256 + k] = f2bf(v);
    }
  } else {
    // precompute block
    for (int idx = tid; idx < 17 * 64; idx += 256) {
      int hg = idx >> 6, k = idx & 63;
      const float* We; const float* ae; int Hh, h;
      if (hg < 8)       { We = We0; ae = ae0; Hh = 8; h = hg; }
      else if (hg < 16) { We = We1; ae = ae1; Hh = 8; h = hg - 8; }
      else              { We = We2; ae = ae2; Hh = 1; h = 0; }
      float s = 0.f;
      for (int d = 0; d < 64; ++d) s += We[(size_t)k * Hh * 64 + h * 64 + d] * ae[h * 64 + d];
      wae[hg][k] = s;
    }
    __syncthreads();
    for (int id = tid; id < 85; id += 256) {
      const float* emb; int Hh, t, h, hg, base;
      if (id < 40)      { emb = emb0; Hh = 8; t = id / 8;  h = id % 8; hg = h;      base = 0;  }
      else if (id < 80) { int i = id - 40; emb = emb1; Hh = 8; t = i / 8; h = i % 8; hg = 8 + h; base = 40; }
      else              { int i = id - 80; emb = emb2; Hh = 1; t = i;    h = 0;     hg = 16;    base = 80; }
      float s = 0.f;
      for (int k = 0; k < 64; ++k) s += emb[t * 64 + k] * wae[hg][k];
      eterm[base + t * Hh + h] = s;
    }
    for (int idx = tid; idx < 96; idx += 256) {
      int t = idx / 32, o = idx % 32;
      float s = 0.f;
      for (int k = 0; k < 32; ++k) s += ntype_emb[t * 32 + k] * W_ntype[k * 32 + o];
      ntf[idx] = s;
    }
    for (int i2 = tid; i2 < 128; i2 += 256) {
      int l = i2 >> 6, j = i2 & 63;
      float u = ln2_b[l] * DW1[l * 64 + j] + Db1[l * 64 + j];
      float g = 0.5f * u * (1.0f + erff(u * 0.7071067811865476f));
      red[i2] = g * DW2[l * 64 + j];
    }
    __syncthreads();
    if (tid == 0) {
      float delta = 0.f;
      for (int l = 0; l < 2; ++l) {
        float vs = ln1_b[l] * Wv[l] + bv[l];
        delta += vs * Wo[l] + bo[l] + Db2[l];
      }
      for (int i = 0; i < 128; ++i) delta += red[i];
      *dadelta = delta;
    }
  }
}

// ============================================================
// Input projection -> Hb bf16
// ============================================================
__global__ void __launch_bounds__(256) inproj_kernel(
    const float* __restrict__ feats, const float* __restrict__ fc_W,
    const float* __restrict__ fc_b, const float* __restrict__ ntf,
    const int* __restrict__ node_type, u16* __restrict__ hb) {
  int t = blockIdx.x * 256 + threadIdx.x;
  if (t >= kN * 32) return;
  int n = t >> 5, o = t & 31;
  int ty = n / 8000;
  const float* fr = &feats[(size_t)n * 128];
  const float* w  = &fc_W[(size_t)ty * 4096 + o];
  float s = fc_b[ty * 32 + o];
  #pragma unroll
  for (int k = 0; k < 128; k += 4) {
    float4 f = *(const float4*)&fr[k];
    s += f.x * w[(k + 0) * 32] + f.y * w[(k + 1) * 32]
       + f.z * w[(k + 2) * 32] + f.w * w[(k + 3) * 32];
  }
  s = (s < 0.f) ? 0.01f * s : s;
  hb[t] = f2bf(s * ntf[node_type[n] * 32 + o]);
}

// ============================================================
// bf16 MFMA GEMM, whole-K LDS staging, ONE barrier per block.
//   cols [0,N1) -> featb bf16; [N1,N1+HH) -> el; [..+HH) -> er;
//   [..,..+N2) -> res+bias -> resb bf16 / resf f32.
// 64x64 tile, 4 waves (2x2), each 32x32 via 2x2 16x16x32 frags.
// XOR-swizzled LDS (T2) for conflict-free ds_read_b128.
// ============================================================
template <int K>
__global__ void __launch_bounds__(256) mfma_gemm_kernel(
    const u16* __restrict__ A, const u16* __restrict__ WT,
    const float* __restrict__ bias,
    u16* __restrict__ featb, float* __restrict__ el, float* __restrict__ er,
    u16* __restrict__ resb, float* __restrict__ resf,
    int N1, int HH, int N2) {
  constexpr int RB = K * 2;            // row bytes
  constexpr int CPR = K / 8;           // 16B chunks per row
  __shared__ __align__(16) u16 As[64 * K];
  __shared__ __align__(16) u16 Bs[64 * K];
  const int tid = threadIdx.x;
  const int l = tid & 63;
  const int w = tid >> 6;
  const int wm = w >> 1, wn = w & 1;
  const int m0 = blockIdx.y * 64;
  const int n0 = blockIdx.x * 64;
  const int kslot = l >> 4;
  const int l15 = l & 15;

  // stage A and B tiles fully (coalesced global, swizzled LDS)
  #pragma unroll
  for (int c = tid; c < 64 * CPR; c += 256) {
    int row = c / CPR, ch = c - row * CPR;
    int off = (row * RB + ch * 16) ^ ((row & 7) << 4);
    uint4 va = *(const uint4*)(A + (size_t)(m0 + row) * K + ch * 8);
    *(uint4*)((char*)As + off) = va;
    uint4 vb = *(const uint4*)(WT + (size_t)(n0 + row) * K + ch * 8);
    *(uint4*)((char*)Bs + off) = vb;
  }
  __syncthreads();

  float4v acc[2][2];
  #pragma unroll
  for (int f = 0; f < 2; ++f)
    #pragma unroll
    for (int g = 0; g < 2; ++g) { acc[f][g][0]=0.f; acc[f][g][1]=0.f; acc[f][g][2]=0.f; acc[f][g][3]=0.f; }

  #pragma unroll
  for (int kc = 0; kc < K; kc += 32) {
    short8 af[2], bf[2];
    #pragma unroll
    for (int f = 0; f < 2; ++f) {
      int row = wm * 32 + f * 16 + l15;
      int off = (row * RB + kc * 2 + kslot * 16) ^ ((row & 7) << 4);
      af[f] = *(const short8*)((const char*)As + off);
    }
    #pragma unroll
    for (int g = 0; g < 2; ++g) {
      int n = wn * 32 + g * 16 + l15;
      int off = (n * RB + kc * 2 + kslot * 16) ^ ((n & 7) << 4);
      bf[g] = *(const short8*)((const char*)Bs + off);
    }
    #pragma unroll
    for (int f = 0; f < 2; ++f)
      #pragma unroll
      for (int g = 0; g < 2; ++g)
        acc[f][g] = __builtin_amdgcn_mfma_f32_16x16x32_bf16(af[f], bf[g], acc[f][g], 0, 0, 0);
  }

  const int rbase = kslot * 4;
  #pragma unroll
  for (int f = 0; f < 2; ++f) {
    #pragma unroll
    for (int g = 0; g < 2; ++g) {
      int gc = n0 + wn * 32 + g * 16 + l15;
      #pragma unroll
      for (int reg = 0; reg < 4; ++reg) {
        int gr = m0 + wm * 32 + f * 16 + rbase + reg;
        float v = acc[f][g][reg];
        if (gc < N1) {
          featb[(size_t)gr * N1 + gc] = f2bf(v);
        } else if (gc < N1 + HH) {
          el[(size_t)gr * HH + (gc - N1)] = v;
        } else if (gc < N1 + 2 * HH) {
          er[(size_t)gr * HH + (gc - N1 - HH)] = v;
        } else if (gc < N1 + 2 * HH + N2) {
          int c2 = gc - N1 - 2 * HH;
          float vv = v + bias[c2];
          if (resb) resb[(size_t)gr * N2 + c2] = f2bf(vv);
          else      resf[(size_t)gr * N2 + c2] = vv;
        }
      }
    }
  }
}

// ============================================================
// Edge-softmax aggregation (HH=8): ONE wave per node.
// lane = h*8+s: head h, dim-quarter s (4 dims, ushort4 8B).
// Pass 1: 8 s-lanes/head stride edges; shfl_xor(1,2,4) merge.
// Pass 2: 8-edge chunks — each lane computes a for (edge i+s, head h)
//   => ONE exp per (edge,head); broadcast a_j / src_j via shfl;
//   8 independent coalesced 512B featb reads in flight per chunk.
// ============================================================
template <bool WRITE_A0, bool READ_A0, bool BIAS_INIT, bool ACT>
__global__ void __launch_bounds__(256) agg8w_kernel(
    const int* __restrict__ row_start, const int* __restrict__ edge_ids,
    const int* __restrict__ src, const int* __restrict__ ef,
    const float* __restrict__ el, const float* __restrict__ er,
    const float* __restrict__ eterm,        // [NE][8]
    const u16* __restrict__ featb,          // [N][256] bf16
    const float* __restrict__ bias,         // [256] (BIAS_INIT)
    _Float16* __restrict__ a0h,             // [E][8]
    const u16* __restrict__ accb,           // [N][256] bf16 (else)
    u16* __restrict__ outb) {               // [N][256] bf16
  int n = (blockIdx.x * 256 + threadIdx.x) >> 6;
  if (n >= kN) return;
  int l = threadIdx.x & 63;
  int h = l >> 3, s = l & 7;
  int s0 = row_start[n], s1 = row_start[n + 1];
  float ern = er[n * 8 + h];
  float et0 = eterm[0 * 8 + h], et1 = eterm[1 * 8 + h], et2 = eterm[2 * 8 + h];
  float et3 = eterm[3 * 8 + h], et4 = eterm[4 * 8 + h];
  // ---- pass 1: per-lane online (max,sum) over every 8th edge ----
  float m = -1e30f, ssum = 0.f;
  for (int i = s0 + s; i < s1; i += 8) {
    int e = edge_ids[i];
    int efc = ef[e];
    float etv = (efc == 0) ? et0 : (efc == 1) ? et1 : (efc == 2) ? et2 : (efc == 3) ? et3 : et4;
    float lg = el[src[e] * 8 + h] + ern + etv;
    lg = (lg < 0.f) ? 0.2f * lg : lg;
    if (lg > m) { ssum = ssum * expf(m - lg) + 1.f; m = lg; }
    else        { ssum += expf(lg - m); }
  }
  #pragma unroll
  for (int mk = 1; mk <= 4; mk <<= 1) {
    float om = __shfl_xor(m, mk);
    float os = __shfl_xor(ssum, mk);
    float nm = fmaxf(m, om);
    ssum = ssum * expf(m - nm) + os * expf(om - nm);
    m = nm;
  }
  float inv = 1.f / ssum;
  // ---- acc init (4 dims per lane) ----
  const size_t rowoff = (size_t)n * 256 + h * 32 + s * 4;
  float4 acc;
  if (BIAS_INIT) {
    acc = *(const float4*)(bias + h * 32 + s * 4);
  } else {
    ushort4 rv = *(const ushort4*)(accb + rowoff);
    acc = make_float4(bf2f(rv.x), bf2f(rv.y), bf2f(rv.z), bf2f(rv.w));
  }
  // ---- pass 2: 8-edge chunks, dedup'd a computation ----
  int i = s0;
  for (; i + 8 <= s1; i += 8) {
    int e = edge_ids[i + s];
    int sek = src[e];
    int efc = ef[e];
    float etv = (efc == 0) ? et0 : (efc == 1) ? et1 : (efc == 2) ? et2 : (efc == 3) ? et3 : et4;
    float lg = el[sek * 8 + h] + ern + etv;
    lg = (lg < 0.f) ? 0.2f * lg : lg;
    float am = expf(lg - m) * inv;
    if (WRITE_A0) a0h[(size_t)e * 8 + h] = (_Float16)am;
    if (READ_A0)  am = am * (1.f - kAlpha) + (float)a0h[(size_t)e * 8 + h] * kAlpha;
    #pragma unroll
    for (int j = 0; j < 8; ++j) {
      float aj = __shfl(am, (h << 3) + j);
      int sej = __shfl(sek, j);
      ushort4 fv = *(const ushort4*)(featb + (size_t)sej * 256 + h * 32 + s * 4);
      acc.x = fmaf(aj, bf2f(fv.x), acc.x);
      acc.y = fmaf(aj, bf2f(fv.y), acc.y);
      acc.z = fmaf(aj, bf2f(fv.z), acc.z);
      acc.w = fmaf(aj, bf2f(fv.w), acc.w);
    }
  }
  if (i < s1) {
    int cnt = s1 - i;
    float am = 0.f; int sek = 0;
    if (s < cnt) {
      int e = edge_ids[i + s];
      sek = src[e];
      int efc = ef[e];
      float etv = (efc == 0) ? et0 : (efc == 1) ? et1 : (efc == 2) ? et2 : (efc == 3) ? et3 : et4;
      float lg = el[sek * 8 + h] + ern + etv;
      lg = (lg < 0.f) ? 0.2f * lg : lg;
      am = expf(lg - m) * inv;
      if (WRITE_A0) a0h[(size_t)e * 8 + h] = (_Float16)am;
      if (READ_A0)  am = am * (1.f - kAlpha) + (float)a0h[(size_t)e * 8 + h] * kAlpha;
    }
    for (int j = 0; j < cnt; ++j) {
      float aj = __shfl(am, (h << 3) + j);
      int sej = __shfl(sek, j);
      ushort4 fv = *(const ushort4*)(featb + (size_t)sej * 256 + h * 32 + s * 4);
      acc.x = fmaf(aj, bf2f(fv.x), acc.x);
      acc.y = fmaf(aj, bf2f(fv.y), acc.y);
      acc.z = fmaf(aj, bf2f(fv.z), acc.z);
      acc.w = fmaf(aj, bf2f(fv.w), acc.w);
    }
  }
  if (ACT) {
    acc.x = (acc.x > 0.f) ? acc.x : expm1f(acc.x);
    acc.y = (acc.y > 0.f) ? acc.y : expm1f(acc.y);
    acc.z = (acc.z > 0.f) ? acc.z : expm1f(acc.z);
    acc.w = (acc.w > 0.f) ? acc.w : expm1f(acc.w);
  }
  ushort4 pw;
  pw.x = f2bf(acc.x); pw.y = f2bf(acc.y); pw.z = f2bf(acc.z); pw.w = f2bf(acc.w);
  *(ushort4*)(outb + rowoff) = pw;
}

// ============================================================
// Fused L2 aggregation (HH=1, thread-per-node) + final head.
// ============================================================
__global__ void __launch_bounds__(256) agg1t_final_kernel(
    const int* __restrict__ row_start, const int* __restrict__ edge_ids,
    const int* __restrict__ src, const int* __restrict__ ef,
    const float* __restrict__ el, const float* __restrict__ er,
    const float* __restrict__ eterm,        // [NE]
    const u16* __restrict__ featb,          // [N][32] bf16
    const float* __restrict__ S2,           // [N][32] f32 (res+bias)
    const float* __restrict__ ntf, const int* __restrict__ node_type,
    const float* __restrict__ dadelta,
    const float* __restrict__ finalW, const float* __restrict__ logitsW,
    float* __restrict__ out) {
  int n = blockIdx.x * 256 + threadIdx.x;
  if (n >= kN) return;
  int s0 = row_start[n], s1 = row_start[n + 1];
  float ern = er[n];
  float et0 = eterm[0], et1 = eterm[1], et2 = eterm[2], et3 = eterm[3], et4 = eterm[4];
  float acc[32];
  #pragma unroll
  for (int d2 = 0; d2 < 8; ++d2) {
    float4 v = *(const float4*)&S2[(size_t)n * 32 + d2 * 4];
    acc[d2*4] = v.x; acc[d2*4+1] = v.y; acc[d2*4+2] = v.z; acc[d2*4+3] = v.w;
  }
  if (s0 < s1) {
    float m = -1e30f, ssum = 0.f;
    for (int i = s0; i < s1; ++i) {
      int e = edge_ids[i];
      int efc = ef[e];
      float etv = (efc == 0) ? et0 : (efc == 1) ? et1 : (efc == 2) ? et2 : (efc == 3) ? et3 : et4;
      float lg = el[src[e]] + ern + etv;
      lg = (lg < 0.f) ? 0.2f * lg : lg;
      if (lg > m) { ssum = ssum * expf(m - lg) + 1.f; m = lg; }
      else        { ssum += expf(lg - m); }
    }
    float inv = 1.f / ssum;
    int e0 = 0, se0 = 0, ef0 = 0;
    e0 = edge_ids[s0]; se0 = src[e0]; ef0 = ef[e0];
    for (int i = s0; i < s1; ++i) {
      int e = e0, se = se0, efc = ef0;
      if (i + 1 < s1) { e0 = edge_ids[i + 1]; se0 = src[e0]; ef0 = ef[e0]; }
      float etv = (efc == 0) ? et0 : (efc == 1) ? et1 : (efc == 2) ? et2 : (efc == 3) ? et3 : et4;
      float lg = el[se] + ern + etv;
      lg = (lg < 0.f) ? 0.2f * lg : lg;
      float a = expf(lg - m) * inv;
      float f[32];
      bfrow32(&featb[(size_t)se * 32], f);
      #pragma unroll
      for (int d = 0; d < 32; ++d) acc[d] = fmaf(a, f[d], acc[d]);
    }
  }
  // ---- final head ----
  float delta = dadelta[0];
  const float* nt = &ntf[node_type[n] * 32];
  float a_[32], b_[32];
  float na = 0.f, nb = 0.f;
  #pragma unroll
  for (int d = 0; d < 32; ++d) {
    float x = acc[d];
    a_[d] = x; na += x * x;
    float y = x * nt[d] + delta;
    b_[d] = y; nb += y * y;
  }
  float inva = 1.f / fmaxf(sqrtf(na), 1e-12f);
  float invb = 1.f / fmaxf(sqrtf(nb), 1e-12f);
  #pragma unroll
  for (int d = 0; d < 32; ++d) { a_[d] *= inva; b_[d] *= invb; }
  float lg[16];
  #pragma unroll
  for (int c = 0; c < 16; ++c) lg[c] = 0.f;
  for (int o = 0; o < 32; ++o) {
    float s = 0.f;
    #pragma unroll
    for (int d = 0; d < 32; ++d)
      s += a_[d] * finalW[d * 32 + o] + b_[d] * finalW[(32 + d) * 32 + o];
    s = fmaxf(s, 0.f);
    #pragma unroll
    for (int c = 0; c < 16; ++c) lg[c] += s * logitsW[o * 16 + c];
  }
  float nl = 0.f;
  #pragma unroll
  for (int c = 0; c < 16; ++c) nl += lg[c] * lg[c];
  float invl = 1.f / fmaxf(sqrtf(nl), 1e-12f);
  #pragma unroll
  for (int c = 0; c < 16; ++c) out[(size_t)n * 16 + c] = lg[c] * invl;
}

// ============================================================
extern "C" void kernel_launch(void* const* d_in, const int* in_sizes, int n_in,
                              void* d_out, int out_size, void* d_ws, size_t ws_size,
                              hipStream_t stream) {
  const float* feats     = (const float*)d_in[0];
  const int*   e_feat    = (const int*)d_in[1];
  const int*   node_type = (const int*)d_in[2];
  const int*   src       = (const int*)d_in[3];
  const int*   dst       = (const int*)d_in[4];
  const float* fc_W      = (const float*)d_in[5];
  const float* fc_b      = (const float*)d_in[6];
  const float* ntype_emb = (const float*)d_in[7];
  const float* W_ntype   = (const float*)d_in[8];
  const float* ta_edge_emb[3] = {(const float*)d_in[9],  (const float*)d_in[16], (const float*)d_in[24]};
  const float* ta_W[3]        = {(const float*)d_in[10], (const float*)d_in[17], (const float*)d_in[25]};
  const float* ta_We[3]       = {(const float*)d_in[11], (const float*)d_in[18], (const float*)d_in[26]};
  const float* ta_al[3]       = {(const float*)d_in[12], (const float*)d_in[19], (const float*)d_in[27]};
  const float* ta_ar[3]       = {(const float*)d_in[13], (const float*)d_in[20], (const float*)d_in[28]};
  const float* ta_ae[3]       = {(const float*)d_in[14], (const float*)d_in[21], (const float*)d_in[29]};
  const float* ta_bias[3]     = {(const float*)d_in[15], (const float*)d_in[22], (const float*)d_in[30]};
  const float* ta1_res_W = (const float*)d_in[23];
  const float* ta2_res_W = (const float*)d_in[31];
  const float* da_ln1_b  = (const float*)d_in[33];
  const float* da_Wv     = (const float*)d_in[38];
  const float* da_bv     = (const float*)d_in[39];
  const float* da_Wo     = (const float*)d_in[40];
  const float* da_bo     = (const float*)d_in[41];
  const float* da_ln2_b  = (const float*)d_in[43];
  const float* da_W1     = (const float*)d_in[44];
  const float* da_b1     = (const float*)d_in[45];
  const float* da_W2     = (const float*)d_in[46];
  const float* da_b2     = (const float*)d_in[47];
  const float* final_W   = (const float*)d_in[48];
  const float* logits_W  = (const float*)d_in[49];
  float* out = (float*)d_out;

  // ---- workspace layout (~51.3 MB, proven safe) ----
  char* base = (char*)d_ws;
  int* iws       = (int*)base;
  int* counts    = iws;
  int* cursor    = iws + kN;
  int* row_start = iws + 2 * kN;
  int* edge_ids  = iws + 2 * kN + kN + 1;
  char* p = base + (size_t)456004 * 4;
  float* ntf = (float*)p;                     p += 512;
  float* etm = (float*)p;                     p += 512;
  float* dad = (float*)p;                     p += 64;
  float* el  = (float*)p;                     p += (size_t)kN * 8 * 4;
  float* er  = (float*)p;                     p += (size_t)kN * 8 * 4;
  float* S2  = (float*)p;                     p += (size_t)kN * 32 * 4;
  u16*   Hb  = (u16*)p;                       p += (size_t)kN * 32 * 2;
  _Float16* a0h = (_Float16*)p;               p += (size_t)kE * 8 * 2;
  u16* featb = (u16*)p;                       p += (size_t)kN * 256 * 2;
  u16* Rb0   = (u16*)p;                       p += (size_t)kN * 256 * 2;
  u16* Rpr   = (u16*)p;                       p += (size_t)kN * 256 * 2;
  u16* WT0   = (u16*)p;                       p += (size_t)320 * 32 * 2;
  u16* WT1   = (u16*)p;                       p += (size_t)576 * 256 * 2;
  u16* WT2   = (u16*)p;                       p += (size_t)128 * 256 * 2;

  // --- CSR build ---
  zero_ints_kernel<<<(2 * kN + 255) / 256, 256, 0, stream>>>(counts, 2 * kN);
  count_kernel<<<kE / 256, 256, 0, stream>>>(dst, counts);
  scan_kernel<<<1, 1024, 0, stream>>>(counts, row_start);
  scatter_kernel<<<kE / 256, 256, 0, stream>>>(dst, row_start, cursor, edge_ids);

  // --- merged precompute + pack ---
  prepack_kernel<<<745, 256, 0, stream>>>(
      ta_W[0], ta_al[0], ta_ar[0],
      ta_W[1], ta_al[1], ta_ar[1], ta1_res_W,
      ta_W[2], ta_al[2], ta_ar[2], ta2_res_W,
      WT0, WT1, WT2,
      ntype_emb, W_ntype,
      ta_edge_emb[0], ta_We[0], ta_ae[0],
      ta_edge_emb[1], ta_We[1], ta_ae[1],
      ta_edge_emb[2], ta_We[2], ta_ae[2],
      da_ln1_b, da_Wv, da_bv, da_Wo, da_bo,
      da_ln2_b, da_W1, da_b1, da_W2, da_b2,
      ntf, etm, dad);

  // --- input projection -> Hb bf16 ---
  inproj_kernel<<<(kN * 32) / 256, 256, 0, stream>>>(feats, fc_W, fc_b, ntf, node_type, Hb);

  // --- TA layer 0: GEMM (feat+el+er) then wave-agg (bias init, elu, write a0) ---
  mfma_gemm_kernel<32><<<dim3(5, kN / 64), 256, 0, stream>>>(
      Hb, WT0, nullptr, featb, el, er, nullptr, nullptr, 256, 8, 0);
  agg8w_kernel<true, false, true, true><<<kN / 4, 256, 0, stream>>>(
      row_start, edge_ids, src, e_feat, el, er, etm, featb, ta_bias[0], a0h, nullptr, Rb0);

  // --- TA layer 1: fused GEMM (feat+el+er+res) then wave-agg (acc=res, blend a0, elu) ---
  mfma_gemm_kernel<256><<<dim3(9, kN / 64), 256, 0, stream>>>(
      Rb0, WT1, ta_bias[1], featb, el, er, Rpr, nullptr, 256, 8, 256);
  agg8w_kernel<false, true, false, true><<<kN / 4, 256, 0, stream>>>(
      row_start, edge_ids, src, e_feat, el, er, etm + 40, featb, nullptr, a0h, Rpr, Rpr);

  // --- TA layer 2: fused GEMM (feat+el+er+res f32) then fused agg+final ---
  mfma_gemm_kernel<256><<<dim3(2, kN / 64), 256, 0, stream>>>(
      Rpr, WT2, ta_bias[2], featb, el, er, nullptr, S2, 32, 1, 32);
  agg1t_final_kernel<<<(kN + 255) / 256, 256, 0, stream>>>(
      row_start, edge_ids, src, e_feat, el, er, etm + 80, featb, S2,
      ntf, node_type, dad, final_W, logits_W, out);
}

// Round 6
// 487.226 us; speedup vs baseline: 1.3590x; 1.0613x over previous
//
#include <hip/hip_runtime.h>
#include <math.h>

// ---------------- problem constants ----------------
constexpr int kN = 24000;     // nodes
constexpr int kE = 384000;    // edges
constexpr float kAlpha = 0.05f;

typedef unsigned int   u32;
typedef unsigned short u16;
typedef __attribute__((ext_vector_type(8))) short short8;
typedef __attribute__((ext_vector_type(4))) float float4v;

// ---- bf16 helpers (internal storage; RNE) ----
__device__ __forceinline__ float bf2f(u16 x) { return __uint_as_float(((u32)x) << 16); }
__device__ __forceinline__ u16 f2bf(float f) {
  u32 u = __float_as_uint(f);
  return (u16)((u + 0x7fffu + ((u >> 16) & 1u)) >> 16);
}

// ============================================================
// CSR build
// ============================================================
__global__ void __launch_bounds__(256) zero_ints_kernel(int* __restrict__ p, int n) {
  int i = blockIdx.x * 256 + threadIdx.x;
  if (i < n) p[i] = 0;
}

__global__ void __launch_bounds__(256) count_kernel(const int* __restrict__ dst,
                                                    int* __restrict__ counts) {
  int e = blockIdx.x * 256 + threadIdx.x;
  if (e < kE) atomicAdd(&counts[dst[e]], 1);
}

__global__ void __launch_bounds__(1024) scan_kernel(const int* __restrict__ counts,
                                                    int* __restrict__ row_start) {
  __shared__ int wsum[16];
  __shared__ int carry_s;
  int tid = threadIdx.x, lane = tid & 63, wid = tid >> 6;
  if (tid == 0) { carry_s = 0; row_start[0] = 0; }
  __syncthreads();
  for (int base = 0; base < kN; base += 1024) {
    int x = (base + tid < kN) ? counts[base + tid] : 0;
    #pragma unroll
    for (int off = 1; off < 64; off <<= 1) {
      int y = __shfl_up(x, off);
      if (lane >= off) x += y;
    }
    if (lane == 63) wsum[wid] = x;
    __syncthreads();
    if (tid < 16) {
      int wv = wsum[tid];
      #pragma unroll
      for (int off = 1; off < 16; off <<= 1) {
        int y = __shfl_up(wv, off);
        if (tid >= off) wv += y;
      }
      wsum[tid] = wv;
    }
    __syncthreads();
    int incl = x + carry_s + (wid > 0 ? wsum[wid - 1] : 0);
    if (base + tid < kN) row_start[base + tid + 1] = incl;
    __syncthreads();
    if (tid == 1023) carry_s = incl;
    __syncthreads();
  }
}

__global__ void __launch_bounds__(256) scatter_kernel(const int* __restrict__ dst,
                                                      const int* __restrict__ row_start,
                                                      int* __restrict__ cursor,
                                                      int* __restrict__ edge_ids) {
  int e = blockIdx.x * 256 + threadIdx.x;
  if (e < kE) {
    int n = dst[e];
    int pos = row_start[n] + atomicAdd(&cursor[n], 1);
    edge_ids[pos] = e;
  }
}

// ============================================================
// Merged precompute + weight-pack.
// ============================================================
__global__ void __launch_bounds__(256) prepack_kernel(
    const float* __restrict__ W0, const float* __restrict__ al0, const float* __restrict__ ar0,
    const float* __restrict__ W1, const float* __restrict__ al1, const float* __restrict__ ar1,
    const float* __restrict__ rW1,
    const float* __restrict__ W2, const float* __restrict__ al2, const float* __restrict__ ar2,
    const float* __restrict__ rW2,
    u16* __restrict__ WT0, u16* __restrict__ WT1, u16* __restrict__ WT2,
    const float* __restrict__ ntype_emb, const float* __restrict__ W_ntype,
    const float* __restrict__ emb0, const float* __restrict__ We0, const float* __restrict__ ae0,
    const float* __restrict__ emb1, const float* __restrict__ We1, const float* __restrict__ ae1,
    const float* __restrict__ emb2, const float* __restrict__ We2, const float* __restrict__ ae2,
    const float* __restrict__ ln1_b, const float* __restrict__ Wv, const float* __restrict__ bv,
    const float* __restrict__ Wo, const float* __restrict__ bo,
    const float* __restrict__ ln2_b, const float* __restrict__ DW1, const float* __restrict__ Db1,
    const float* __restrict__ DW2, const float* __restrict__ Db2,
    float* __restrict__ ntf, float* __restrict__ eterm, float* __restrict__ dadelta) {
  __shared__ float wae[17][64];
  __shared__ float red[128];
  int tid = threadIdx.x;
  if (blockIdx.x < 744) {
    const int SZ0 = 320 * 32, SZ1 = 576 * 256;
    int gid = blockIdx.x * 256 + tid;
    float v = 0.f;
    if (gid < SZ0) {
      int n = gid / 32, k = gid % 32;
      if (n < 256) v = W0[k * 256 + n];
      else if (n < 264) { int h = n - 256; for (int d = 0; d < 32; ++d) v += W0[k * 256 + h * 32 + d] * al0[h * 32 + d]; }
      else if (n < 272) { int h = n - 264; for (int d = 0; d < 32; ++d) v += W0[k * 256 + h * 32 + d] * ar0[h * 32 + d]; }
      WT0[n * 32 + k] = f2bf(v);
    } else if (gid < SZ0 + SZ1) {
      int i = gid - SZ0;
      int n = i / 256, k = i % 256;
      if (n < 256) v = W1[k * 256 + n];
      else if (n < 264) { int h = n - 256; for (int d = 0; d < 32; ++d) v += W1[k * 256 + h * 32 + d] * al1[h * 32 + d]; }
      else if (n < 272) { int h = n - 264; for (int d = 0; d < 32; ++d) v += W1[k * 256 + h * 32 + d] * ar1[h * 32 + d]; }
      else if (n < 528) v = rW1[k * 256 + (n - 272)];
      WT1[n * 256 + k] = f2bf(v);
    } else {
      int i = gid - SZ0 - SZ1;
      int n = i / 256, k = i % 256;
      if (n < 32) v = W2[k * 32 + n];
      else if (n == 32) { for (int d = 0; d < 32; ++d) v += W2[k * 32 + d] * al2[d]; }
      else if (n == 33) { for (int d = 0; d < 32; ++d) v += W2[k * 32 + d] * ar2[d]; }
      else if (n < 66) v = rW2[k * 32 + (n - 34)];
      WT2[n * 256 + k] = f2bf(v);
    }
  } else {
    for (int idx = tid; idx < 17 * 64; idx += 256) {
      int hg = idx >> 6, k = idx & 63;
      const float* We; const float* ae; int Hh, h;
      if (hg < 8)       { We = We0; ae = ae0; Hh = 8; h = hg; }
      else if (hg < 16) { We = We1; ae = ae1; Hh = 8; h = hg - 8; }
      else              { We = We2; ae = ae2; Hh = 1; h = 0; }
      float s = 0.f;
      for (int d = 0; d < 64; ++d) s += We[(size_t)k * Hh * 64 + h * 64 + d] * ae[h * 64 + d];
      wae[hg][k] = s;
    }
    __syncthreads();
    for (int id = tid; id < 85; id += 256) {
      const float* emb; int Hh, t, h, hg, base;
      if (id < 40)      { emb = emb0; Hh = 8; t = id / 8;  h = id % 8; hg = h;      base = 0;  }
      else if (id < 80) { int i = id - 40; emb = emb1; Hh = 8; t = i / 8; h = i % 8; hg = 8 + h; base = 40; }
      else              { int i = id - 80; emb = emb2; Hh = 1; t = i;    h = 0;     hg = 16;    base = 80; }
      float s = 0.f;
      for (int k = 0; k < 64; ++k) s += emb[t * 64 + k] * wae[hg][k];
      eterm[base + t * Hh + h] = s;
    }
    for (int idx = tid; idx < 96; idx += 256) {
      int t = idx / 32, o = idx % 32;
      float s = 0.f;
      for (int k = 0; k < 32; ++k) s += ntype_emb[t * 32 + k] * W_ntype[k * 32 + o];
      ntf[idx] = s;
    }
    for (int i2 = tid; i2 < 128; i2 += 256) {
      int l = i2 >> 6, j = i2 & 63;
      float u = ln2_b[l] * DW1[l * 64 + j] + Db1[l * 64 + j];
      float g = 0.5f * u * (1.0f + erff(u * 0.7071067811865476f));
      red[i2] = g * DW2[l * 64 + j];
    }
    __syncthreads();
    if (tid == 0) {
      float delta = 0.f;
      for (int l = 0; l < 2; ++l) {
        float vs = ln1_b[l] * Wv[l] + bv[l];
        delta += vs * Wo[l] + bo[l] + Db2[l];
      }
      for (int i = 0; i < 128; ++i) delta += red[i];
      *dadelta = delta;
    }
  }
}

// ============================================================
// Input projection -> Hb bf16
// ============================================================
__global__ void __launch_bounds__(256) inproj_kernel(
    const float* __restrict__ feats, const float* __restrict__ fc_W,
    const float* __restrict__ fc_b, const float* __restrict__ ntf,
    const int* __restrict__ node_type, u16* __restrict__ hb) {
  int t = blockIdx.x * 256 + threadIdx.x;
  if (t >= kN * 32) return;
  int n = t >> 5, o = t & 31;
  int ty = n / 8000;
  const float* fr = &feats[(size_t)n * 128];
  const float* w  = &fc_W[(size_t)ty * 4096 + o];
  float s = fc_b[ty * 32 + o];
  #pragma unroll
  for (int k = 0; k < 128; k += 4) {
    float4 f = *(const float4*)&fr[k];
    s += f.x * w[(k + 0) * 32] + f.y * w[(k + 1) * 32]
       + f.z * w[(k + 2) * 32] + f.w * w[(k + 3) * 32];
  }
  s = (s < 0.f) ? 0.01f * s : s;
  hb[t] = f2bf(s * ntf[node_type[n] * 32 + o]);
}

// ============================================================
// bf16 MFMA GEMM, whole-K LDS staging, ONE barrier per block.
// ============================================================
template <int K>
__global__ void __launch_bounds__(256) mfma_gemm_kernel(
    const u16* __restrict__ A, const u16* __restrict__ WT,
    const float* __restrict__ bias,
    u16* __restrict__ featb, float* __restrict__ el, float* __restrict__ er,
    u16* __restrict__ resb, float* __restrict__ resf,
    int N1, int HH, int N2) {
  constexpr int RB = K * 2;            // row bytes
  constexpr int CPR = K / 8;           // 16B chunks per row
  __shared__ __align__(16) u16 As[64 * K];
  __shared__ __align__(16) u16 Bs[64 * K];
  const int tid = threadIdx.x;
  const int l = tid & 63;
  const int w = tid >> 6;
  const int wm = w >> 1, wn = w & 1;
  const int m0 = blockIdx.y * 64;
  const int n0 = blockIdx.x * 64;
  const int kslot = l >> 4;
  const int l15 = l & 15;

  #pragma unroll
  for (int c = tid; c < 64 * CPR; c += 256) {
    int row = c / CPR, ch = c - row * CPR;
    int off = (row * RB + ch * 16) ^ ((row & 7) << 4);
    uint4 va = *(const uint4*)(A + (size_t)(m0 + row) * K + ch * 8);
    *(uint4*)((char*)As + off) = va;
    uint4 vb = *(const uint4*)(WT + (size_t)(n0 + row) * K + ch * 8);
    *(uint4*)((char*)Bs + off) = vb;
  }
  __syncthreads();

  float4v acc[2][2];
  #pragma unroll
  for (int f = 0; f < 2; ++f)
    #pragma unroll
    for (int g = 0; g < 2; ++g) { acc[f][g][0]=0.f; acc[f][g][1]=0.f; acc[f][g][2]=0.f; acc[f][g][3]=0.f; }

  #pragma unroll
  for (int kc = 0; kc < K; kc += 32) {
    short8 af[2], bf[2];
    #pragma unroll
    for (int f = 0; f < 2; ++f) {
      int row = wm * 32 + f * 16 + l15;
      int off = (row * RB + kc * 2 + kslot * 16) ^ ((row & 7) << 4);
      af[f] = *(const short8*)((const char*)As + off);
    }
    #pragma unroll
    for (int g = 0; g < 2; ++g) {
      int n = wn * 32 + g * 16 + l15;
      int off = (n * RB + kc * 2 + kslot * 16) ^ ((n & 7) << 4);
      bf[g] = *(const short8*)((const char*)Bs + off);
    }
    #pragma unroll
    for (int f = 0; f < 2; ++f)
      #pragma unroll
      for (int g = 0; g < 2; ++g)
        acc[f][g] = __builtin_amdgcn_mfma_f32_16x16x32_bf16(af[f], bf[g], acc[f][g], 0, 0, 0);
  }

  const int rbase = kslot * 4;
  #pragma unroll
  for (int f = 0; f < 2; ++f) {
    #pragma unroll
    for (int g = 0; g < 2; ++g) {
      int gc = n0 + wn * 32 + g * 16 + l15;
      #pragma unroll
      for (int reg = 0; reg < 4; ++reg) {
        int gr = m0 + wm * 32 + f * 16 + rbase + reg;
        float v = acc[f][g][reg];
        if (gc < N1) {
          featb[(size_t)gr * N1 + gc] = f2bf(v);
        } else if (gc < N1 + HH) {
          el[(size_t)gr * HH + (gc - N1)] = v;
        } else if (gc < N1 + 2 * HH) {
          er[(size_t)gr * HH + (gc - N1 - HH)] = v;
        } else if (gc < N1 + 2 * HH + N2) {
          int c2 = gc - N1 - 2 * HH;
          float vv = v + bias[c2];
          if (resb) resb[(size_t)gr * N2 + c2] = f2bf(vv);
          else      resf[(size_t)gr * N2 + c2] = vv;
        }
      }
    }
  }
}

// ============================================================
// Edge-softmax aggregation (HH=8): ONE wave per node.
// Pass 2: 8-edge chunks, 1 exp per (edge,head), shfl broadcast.
// ============================================================
template <bool WRITE_A0, bool READ_A0, bool BIAS_INIT, bool ACT>
__global__ void __launch_bounds__(256) agg8w_kernel(
    const int* __restrict__ row_start, const int* __restrict__ edge_ids,
    const int* __restrict__ src, const int* __restrict__ ef,
    const float* __restrict__ el, const float* __restrict__ er,
    const float* __restrict__ eterm,        // [NE][8]
    const u16* __restrict__ featb,          // [N][256] bf16
    const float* __restrict__ bias,         // [256] (BIAS_INIT)
    _Float16* __restrict__ a0h,             // [E][8]
    const u16* __restrict__ accb,           // [N][256] bf16 (else)
    u16* __restrict__ outb) {               // [N][256] bf16
  int n = (blockIdx.x * 256 + threadIdx.x) >> 6;
  if (n >= kN) return;
  int l = threadIdx.x & 63;
  int h = l >> 3, s = l & 7;
  int s0 = row_start[n], s1 = row_start[n + 1];
  float ern = er[n * 8 + h];
  float et0 = eterm[0 * 8 + h], et1 = eterm[1 * 8 + h], et2 = eterm[2 * 8 + h];
  float et3 = eterm[3 * 8 + h], et4 = eterm[4 * 8 + h];
  float m = -1e30f, ssum = 0.f;
  for (int i = s0 + s; i < s1; i += 8) {
    int e = edge_ids[i];
    int efc = ef[e];
    float etv = (efc == 0) ? et0 : (efc == 1) ? et1 : (efc == 2) ? et2 : (efc == 3) ? et3 : et4;
    float lg = el[src[e] * 8 + h] + ern + etv;
    lg = (lg < 0.f) ? 0.2f * lg : lg;
    if (lg > m) { ssum = ssum * expf(m - lg) + 1.f; m = lg; }
    else        { ssum += expf(lg - m); }
  }
  #pragma unroll
  for (int mk = 1; mk <= 4; mk <<= 1) {
    float om = __shfl_xor(m, mk);
    float os = __shfl_xor(ssum, mk);
    float nm = fmaxf(m, om);
    ssum = ssum * expf(m - nm) + os * expf(om - nm);
    m = nm;
  }
  float inv = 1.f / ssum;
  const size_t rowoff = (size_t)n * 256 + h * 32 + s * 4;
  float4 acc;
  if (BIAS_INIT) {
    acc = *(const float4*)(bias + h * 32 + s * 4);
  } else {
    ushort4 rv = *(const ushort4*)(accb + rowoff);
    acc = make_float4(bf2f(rv.x), bf2f(rv.y), bf2f(rv.z), bf2f(rv.w));
  }
  int i = s0;
  for (; i + 8 <= s1; i += 8) {
    int e = edge_ids[i + s];
    int sek = src[e];
    int efc = ef[e];
    float etv = (efc == 0) ? et0 : (efc == 1) ? et1 : (efc == 2) ? et2 : (efc == 3) ? et3 : et4;
    float lg = el[sek * 8 + h] + ern + etv;
    lg = (lg < 0.f) ? 0.2f * lg : lg;
    float am = expf(lg - m) * inv;
    if (WRITE_A0) a0h[(size_t)e * 8 + h] = (_Float16)am;
    if (READ_A0)  am = am * (1.f - kAlpha) + (float)a0h[(size_t)e * 8 + h] * kAlpha;
    #pragma unroll
    for (int j = 0; j < 8; ++j) {
      float aj = __shfl(am, (h << 3) + j);
      int sej = __shfl(sek, j);
      ushort4 fv = *(const ushort4*)(featb + (size_t)sej * 256 + h * 32 + s * 4);
      acc.x = fmaf(aj, bf2f(fv.x), acc.x);
      acc.y = fmaf(aj, bf2f(fv.y), acc.y);
      acc.z = fmaf(aj, bf2f(fv.z), acc.z);
      acc.w = fmaf(aj, bf2f(fv.w), acc.w);
    }
  }
  if (i < s1) {
    int cnt = s1 - i;
    float am = 0.f; int sek = 0;
    if (s < cnt) {
      int e = edge_ids[i + s];
      sek = src[e];
      int efc = ef[e];
      float etv = (efc == 0) ? et0 : (efc == 1) ? et1 : (efc == 2) ? et2 : (efc == 3) ? et3 : et4;
      float lg = el[sek * 8 + h] + ern + etv;
      lg = (lg < 0.f) ? 0.2f * lg : lg;
      am = expf(lg - m) * inv;
      if (WRITE_A0) a0h[(size_t)e * 8 + h] = (_Float16)am;
      if (READ_A0)  am = am * (1.f - kAlpha) + (float)a0h[(size_t)e * 8 + h] * kAlpha;
    }
    for (int j = 0; j < cnt; ++j) {
      float aj = __shfl(am, (h << 3) + j);
      int sej = __shfl(sek, j);
      ushort4 fv = *(const ushort4*)(featb + (size_t)sej * 256 + h * 32 + s * 4);
      acc.x = fmaf(aj, bf2f(fv.x), acc.x);
      acc.y = fmaf(aj, bf2f(fv.y), acc.y);
      acc.z = fmaf(aj, bf2f(fv.z), acc.z);
      acc.w = fmaf(aj, bf2f(fv.w), acc.w);
    }
  }
  if (ACT) {
    acc.x = (acc.x > 0.f) ? acc.x : expm1f(acc.x);
    acc.y = (acc.y > 0.f) ? acc.y : expm1f(acc.y);
    acc.z = (acc.z > 0.f) ? acc.z : expm1f(acc.z);
    acc.w = (acc.w > 0.f) ? acc.w : expm1f(acc.w);
  }
  ushort4 pw;
  pw.x = f2bf(acc.x); pw.y = f2bf(acc.y); pw.z = f2bf(acc.z); pw.w = f2bf(acc.w);
  *(ushort4*)(outb + rowoff) = pw;
}

// ============================================================
// Fused L2 aggregation + final head: 32 LANES PER NODE.
// Block = 256 thr = 8 nodes (2 per wave). lane g = dim.
// Agg: pass1 strided + shfl_xor merge; pass2 chunked dedup'd exp
// with shfl broadcast; coalesced 64B featb row reads.
// Final head: norms via shfl; final_W/logits_W staged in LDS;
// a/b/s handed off via per-slot LDS buffers.
// ============================================================
__global__ void __launch_bounds__(256) aggw1_final_kernel(
    const int* __restrict__ row_start, const int* __restrict__ edge_ids,
    const int* __restrict__ src, const int* __restrict__ ef,
    const float* __restrict__ el, const float* __restrict__ er,
    const float* __restrict__ eterm,        // [NE]
    const u16* __restrict__ featb,          // [N][32] bf16
    const float* __restrict__ S2,           // [N][32] f32 (res+bias)
    const float* __restrict__ ntf, const int* __restrict__ node_type,
    const float* __restrict__ dadelta,
    const float* __restrict__ finalW, const float* __restrict__ logitsW,
    float* __restrict__ out) {
  __shared__ float fWs[2048];     // finalW 64x32
  __shared__ float lWs[512];      // logitsW 32x16
  __shared__ float abuf[8][32];
  __shared__ float bbuf[8][32];
  __shared__ float sbuf[8][32];
  const int tid = threadIdx.x;
  for (int i = tid; i < 2048; i += 256) fWs[i] = finalW[i];
  for (int i = tid; i < 512; i += 256) lWs[i] = logitsW[i];
  const int slot = tid >> 5;            // 0..7
  const int g = tid & 31;               // dim lane
  const int gb = tid & 32;              // group base within wave (0 or 32)
  const int n = blockIdx.x * 8 + slot;  // grid exactly kN/8
  const int s0 = row_start[n], s1 = row_start[n + 1];
  float ern = er[n];
  float et0 = eterm[0], et1 = eterm[1], et2 = eterm[2], et3 = eterm[3], et4 = eterm[4];
  // ---- pass 1 ----
  float m = -1e30f, ssum = 0.f;
  for (int i = s0 + g; i < s1; i += 32) {
    int e = edge_ids[i];
    int efc = ef[e];
    float etv = (efc == 0) ? et0 : (efc == 1) ? et1 : (efc == 2) ? et2 : (efc == 3) ? et3 : et4;
    float lg = el[src[e]] + ern + etv;
    lg = (lg < 0.f) ? 0.2f * lg : lg;
    if (lg > m) { ssum = ssum * expf(m - lg) + 1.f; m = lg; }
    else        { ssum += expf(lg - m); }
  }
  #pragma unroll
  for (int mk = 1; mk <= 16; mk <<= 1) {
    float om = __shfl_xor(m, mk);
    float os = __shfl_xor(ssum, mk);
    float nm = fmaxf(m, om);
    ssum = ssum * expf(m - nm) + os * expf(om - nm);
    m = nm;
  }
  float inv = 1.f / ssum;
  // ---- pass 2: acc = S2 + sum a*feat (lane owns dim g) ----
  float acc = S2[(size_t)n * 32 + g];
  int i = s0;
  for (; i + 32 <= s1; i += 32) {
    int e = edge_ids[i + g];
    int sek = src[e];
    int efc = ef[e];
    float etv = (efc == 0) ? et0 : (efc == 1) ? et1 : (efc == 2) ? et2 : (efc == 3) ? et3 : et4;
    float lg = el[sek] + ern + etv;
    lg = (lg < 0.f) ? 0.2f * lg : lg;
    float am = expf(lg - m) * inv;
    #pragma unroll
    for (int j = 0; j < 32; ++j) {
      float aj = __shfl(am, gb + j);
      int sej = __shfl(sek, gb + j);
      acc = fmaf(aj, bf2f(featb[(size_t)sej * 32 + g]), acc);
    }
  }
  if (i < s1) {
    int cnt = s1 - i;
    float am = 0.f; int sek = 0;
    if (g < cnt) {
      int e = edge_ids[i + g];
      sek = src[e];
      int efc = ef[e];
      float etv = (efc == 0) ? et0 : (efc == 1) ? et1 : (efc == 2) ? et2 : (efc == 3) ? et3 : et4;
      float lg = el[sek] + ern + etv;
      lg = (lg < 0.f) ? 0.2f * lg : lg;
      am = expf(lg - m) * inv;
    }
    for (int j = 0; j < cnt; ++j) {
      float aj = __shfl(am, gb + j);
      int sej = __shfl(sek, gb + j);
      acc = fmaf(aj, bf2f(featb[(size_t)sej * 32 + g]), acc);
    }
  }
  // ---- final head ----
  float delta = dadelta[0];
  float ntv = ntf[node_type[n] * 32 + g];
  float av = acc;
  float bv = acc * ntv + delta;
  float na = av * av, nb = bv * bv;
  #pragma unroll
  for (int mk = 1; mk <= 16; mk <<= 1) {
    na += __shfl_xor(na, mk);
    nb += __shfl_xor(nb, mk);
  }
  float inva = 1.f / fmaxf(sqrtf(na), 1e-12f);
  float invb = 1.f / fmaxf(sqrtf(nb), 1e-12f);
  __syncthreads();                 // fWs/lWs staged (also before abuf writes)
  abuf[slot][g] = av * inva;
  bbuf[slot][g] = bv * invb;
  __syncthreads();
  // lane g = output o
  float s = 0.f;
  #pragma unroll
  for (int d = 0; d < 32; ++d)
    s += abuf[slot][d] * fWs[d * 32 + g] + bbuf[slot][d] * fWs[(32 + d) * 32 + g];
  s = fmaxf(s, 0.f);
  sbuf[slot][g] = s;
  __syncthreads();
  if (g < 16) {
    float lg = 0.f;
    #pragma unroll
    for (int o = 0; o < 32; ++o) lg += sbuf[slot][o] * lWs[o * 16 + g];
    float nl = lg * lg;
    #pragma unroll
    for (int mk = 1; mk <= 8; mk <<= 1) nl += __shfl_xor(nl, mk);
    float invl = 1.f / fmaxf(sqrtf(nl), 1e-12f);
    out[(size_t)n * 16 + g] = lg * invl;
  }
}

// ============================================================
extern "C" void kernel_launch(void* const* d_in, const int* in_sizes, int n_in,
                              void* d_out, int out_size, void* d_ws, size_t ws_size,
                              hipStream_t stream) {
  const float* feats     = (const float*)d_in[0];
  const int*   e_feat    = (const int*)d_in[1];
  const int*   node_type = (const int*)d_in[2];
  const int*   src       = (const int*)d_in[3];
  const int*   dst       = (const int*)d_in[4];
  const float* fc_W      = (const float*)d_in[5];
  const float* fc_b      = (const float*)d_in[6];
  const float* ntype_emb = (const float*)d_in[7];
  const float* W_ntype   = (const float*)d_in[8];
  const float* ta_edge_emb[3] = {(const float*)d_in[9],  (const float*)d_in[16], (const float*)d_in[24]};
  const float* ta_W[3]        = {(const float*)d_in[10], (const float*)d_in[17], (const float*)d_in[25]};
  const float* ta_We[3]       = {(const float*)d_in[11], (const float*)d_in[18], (const float*)d_in[26]};
  const float* ta_al[3]       = {(const float*)d_in[12], (const float*)d_in[19], (const float*)d_in[27]};
  const float* ta_ar[3]       = {(const float*)d_in[13], (const float*)d_in[20], (const float*)d_in[28]};
  const float* ta_ae[3]       = {(const float*)d_in[14], (const float*)d_in[21], (const float*)d_in[29]};
  const float* ta_bias[3]     = {(const float*)d_in[15], (const float*)d_in[22], (const float*)d_in[30]};
  const float* ta1_res_W = (const float*)d_in[23];
  const float* ta2_res_W = (const float*)d_in[31];
  const float* da_ln1_b  = (const float*)d_in[33];
  const float* da_Wv     = (const float*)d_in[38];
  const float* da_bv     = (const float*)d_in[39];
  const float* da_Wo     = (const float*)d_in[40];
  const float* da_bo     = (const float*)d_in[41];
  const float* da_ln2_b  = (const float*)d_in[43];
  const float* da_W1     = (const float*)d_in[44];
  const float* da_b1     = (const float*)d_in[45];
  const float* da_W2     = (const float*)d_in[46];
  const float* da_b2     = (const float*)d_in[47];
  const float* final_W   = (const float*)d_in[48];
  const float* logits_W  = (const float*)d_in[49];
  float* out = (float*)d_out;

  // ---- workspace layout (~51.3 MB, proven safe) ----
  char* base = (char*)d_ws;
  int* iws       = (int*)base;
  int* counts    = iws;
  int* cursor    = iws + kN;
  int* row_start = iws + 2 * kN;
  int* edge_ids  = iws + 2 * kN + kN + 1;
  char* p = base + (size_t)456004 * 4;
  float* ntf = (float*)p;                     p += 512;
  float* etm = (float*)p;                     p += 512;
  float* dad = (float*)p;                     p += 64;
  float* el  = (float*)p;                     p += (size_t)kN * 8 * 4;
  float* er  = (float*)p;                     p += (size_t)kN * 8 * 4;
  float* S2  = (float*)p;                     p += (size_t)kN * 32 * 4;
  u16*   Hb  = (u16*)p;                       p += (size_t)kN * 32 * 2;
  _Float16* a0h = (_Float16*)p;               p += (size_t)kE * 8 * 2;
  u16* featb = (u16*)p;                       p += (size_t)kN * 256 * 2;
  u16* Rb0   = (u16*)p;                       p += (size_t)kN * 256 * 2;
  u16* Rpr   = (u16*)p;                       p += (size_t)kN * 256 * 2;
  u16* WT0   = (u16*)p;                       p += (size_t)320 * 32 * 2;
  u16* WT1   = (u16*)p;                       p += (size_t)576 * 256 * 2;
  u16* WT2   = (u16*)p;                       p += (size_t)128 * 256 * 2;

  // --- CSR build ---
  zero_ints_kernel<<<(2 * kN + 255) / 256, 256, 0, stream>>>(counts, 2 * kN);
  count_kernel<<<kE / 256, 256, 0, stream>>>(dst, counts);
  scan_kernel<<<1, 1024, 0, stream>>>(counts, row_start);
  scatter_kernel<<<kE / 256, 256, 0, stream>>>(dst, row_start, cursor, edge_ids);

  // --- merged precompute + pack ---
  prepack_kernel<<<745, 256, 0, stream>>>(
      ta_W[0], ta_al[0], ta_ar[0],
      ta_W[1], ta_al[1], ta_ar[1], ta1_res_W,
      ta_W[2], ta_al[2], ta_ar[2], ta2_res_W,
      WT0, WT1, WT2,
      ntype_emb, W_ntype,
      ta_edge_emb[0], ta_We[0], ta_ae[0],
      ta_edge_emb[1], ta_We[1], ta_ae[1],
      ta_edge_emb[2], ta_We[2], ta_ae[2],
      da_ln1_b, da_Wv, da_bv, da_Wo, da_bo,
      da_ln2_b, da_W1, da_b1, da_W2, da_b2,
      ntf, etm, dad);

  // --- input projection -> Hb bf16 ---
  inproj_kernel<<<(kN * 32) / 256, 256, 0, stream>>>(feats, fc_W, fc_b, ntf, node_type, Hb);

  // --- TA layer 0 ---
  mfma_gemm_kernel<32><<<dim3(5, kN / 64), 256, 0, stream>>>(
      Hb, WT0, nullptr, featb, el, er, nullptr, nullptr, 256, 8, 0);
  agg8w_kernel<true, false, true, true><<<kN / 4, 256, 0, stream>>>(
      row_start, edge_ids, src, e_feat, el, er, etm, featb, ta_bias[0], a0h, nullptr, Rb0);

  // --- TA layer 1 ---
  mfma_gemm_kernel<256><<<dim3(9, kN / 64), 256, 0, stream>>>(
      Rb0, WT1, ta_bias[1], featb, el, er, Rpr, nullptr, 256, 8, 256);
  agg8w_kernel<false, true, false, true><<<kN / 4, 256, 0, stream>>>(
      row_start, edge_ids, src, e_feat, el, er, etm + 40, featb, nullptr, a0h, Rpr, Rpr);

  // --- TA layer 2: GEMM then fused 32-lane agg + final head ---
  mfma_gemm_kernel<256><<<dim3(2, kN / 64), 256, 0, stream>>>(
      Rpr, WT2, ta_bias[2], featb, el, er, nullptr, S2, 32, 1, 32);
  aggw1_final_kernel<<<kN / 8, 256, 0, stream>>>(
      row_start, edge_ids, src, e_feat, el, er, etm + 80, featb, S2,
      ntf, node_type, dad, final_W, logits_W, out);
}